// Round 1
// 298.017 us; speedup vs baseline: 1.0350x; 1.0350x over previous
//
#include <hip/hip_runtime.h>

// Problem shapes (fixed by setup_inputs)
namespace {
constexpr int B  = 8;
constexpr int N  = 100;
constexpr int C  = 256;
constexpr int H  = 160;
constexpr int W  = 160;
constexpr int NC = 80;     // NUM_CLASSES
constexpr int T  = 1024;   // threads/block = 16 waves
constexpr int NW = 16;     // waves/block
constexpr int RPW = H / NW;// 10 rows per wave
constexpr int SCR = 164;   // per-buffer prefix scratch stride (floats); 164*4=656B, 16B-aligned
}

// image_h / image_w arrive as 1-element arrays of unknown dtype (python
// scalar). Read as int32; if implausible, reinterpret the bits as float32.
__device__ inline float read_dim(const int* p) {
    int i = *p;
    if (i >= 1 && i <= (1 << 26)) return (float)i;
    return __int_as_float(i);
}

// One step of the classic GCN wave64 inclusive scan, VALU-only (no LDS):
// s += dpp_shifted(s). Masked-off / invalid-source lanes contribute old=0.
#define DPP_ADD(s, ctrl, rmask)                                              \
    s += __int_as_float(__builtin_amdgcn_update_dpp(                          \
        0, __float_as_int(s), (ctrl), (rmask), 0xf, false))

extern "C" __global__ void __launch_bounds__(T)
vpe_kernel(const float* __restrict__ features,  // [B,C,H,W]
           const float* __restrict__ boxes,     // [B,N,4]
           const int*   __restrict__ gt,        // [B,N]
           const int*   __restrict__ neg_y,     // [B,NC]
           const int*   __restrict__ neg_x,     // [B,NC]
           const int*   __restrict__ imh_p,     // scalar
           const int*   __restrict__ imw_p,     // scalar
           float*       __restrict__ out)       // [B,NC,C]
{
    // One block per (b,c). Wave-synchronous row pipeline: each wave owns 10
    // rows; the cross-lane row prefix is computed with a DPP scan (pure VALU,
    // no ds_bpermute chain). Per-wave scratch is double-buffered so a single
    // wave_barrier per row suffices. Each lane privately accumulates <=2
    // boxes in VGPRs (NO per-row atomics).
    __shared__ float rs[NW * 2 * SCR]; // 2 buffers/wave, ~52.5 KB
    __shared__ float cls_sum[NC];
    __shared__ int   cls_cnt[NC];
    __shared__ int   bx1m[N], bx2m[N], by1[N], by2[N], bcls[N];
    __shared__ float bwgt[N];

    const int tid  = threadIdx.x;
    const int wave = tid >> 6, lane = tid & 63;
    const int b    = blockIdx.x / C;
    const int c    = blockIdx.x % C;
    const float* plane = features + (size_t)(b * C + c) * (H * W);

    if (tid < NC) { cls_sum[tid] = 0.f; cls_cnt[tid] = 0; }
    __syncthreads();

    // Box setup (uniform per b; recomputed per block — trivial cost).
    if (tid < N) {
        float imw = read_dim(imw_p), imh = read_dim(imh_p);
        float sx = (float)W / imw, sy = (float)H / imh;
        const float* bp = boxes + (size_t)(b * N + tid) * 4;
        int x1 = (int)fminf(fmaxf(floorf(bp[0] * sx), 0.f), (float)W);
        int y1 = (int)fminf(fmaxf(floorf(bp[1] * sy), 0.f), (float)H);
        int x2 = (int)fminf(fmaxf(floorf(bp[2] * sx), 0.f), (float)W);
        int y2 = (int)fminf(fmaxf(floorf(bp[3] * sy), 0.f), (float)H);
        bool valid = (x2 > x1) && (y2 > y1);
        bx1m[tid] = x1 - 1; bx2m[tid] = x2 - 1;
        by1[tid] = y1; by2[tid] = y2;
        int cls = gt[b * N + tid];
        bcls[tid] = valid ? cls : -1;
        bwgt[tid] = 1.f / (float)max((x2 - x1) * (y2 - y1), 1);
        if (valid) atomicAdd(&cls_cnt[cls], 1);
    }
    __syncthreads();
    // Fold the class-count divisor into the per-box weight.
    if (tid < N && bcls[tid] >= 0)
        bwgt[tid] /= (float)max(cls_cnt[bcls[tid]], 1);
    __syncthreads();

    // Per-lane box registers: lane owns boxes nA=lane and nB=lane+64.
    float* buf0 = &rs[(wave * 2 + 0) * SCR];
    float* buf1 = &rs[(wave * 2 + 1) * SCR];
    const int nA = lane, nB = lane + 64;
    const int clsA = bcls[nA];
    const int y1A = by1[nA], y2A = by2[nA], x1A = bx1m[nA], x2A = bx2m[nA];
    const float wA = bwgt[nA];
    int clsB = -1, y1B = 0, y2B = 0, x1B = 0, x2B = 0; float wB = 0.f;
    if (nB < N) {
        clsB = bcls[nB]; y1B = by1[nB]; y2B = by2[nB];
        x1B = bx1m[nB]; x2B = bx2m[nB]; wB = bwgt[nB];
    }

    float accA = 0.f, accB = 0.f;
    const bool ldr = (lane < W / 4);   // 40 loader lanes cover one 640B row

    const float4 z4 = make_float4(0.f, 0.f, 0.f, 0.f);
    const float4* prow = (const float4*)plane + lane;   // row stride W/4

    // Depth-2 software prefetch: loads for row r+2 in flight during row r.
    float4 v  = ldr ? prow[(size_t)wave * (W / 4)] : z4;
    float4 vn = (ldr && RPW > 1) ? prow[(size_t)(wave + NW) * (W / 4)] : z4;

    for (int r = 0; r < RPW; ++r) {
        const int y = wave + (r << 4);
        float4 v2 = z4;
        if (r + 2 < RPW && ldr)
            v2 = prow[(size_t)(y + 2 * NW) * (W / 4)];

        // Lane-local partial prefixes (independent of the scan chain).
        float q1 = v.x, q2 = q1 + v.y, q3 = q2 + v.z, t = q3 + v.w;

        // Wave64 inclusive scan of lane totals — 6 dependent VALU adds.
        float s = t;
        DPP_ADD(s, 0x111, 0xf);   // row_shr:1
        DPP_ADD(s, 0x112, 0xf);   // row_shr:2
        DPP_ADD(s, 0x114, 0xf);   // row_shr:4
        DPP_ADD(s, 0x118, 0xf);   // row_shr:8
        DPP_ADD(s, 0x142, 0xa);   // row_bcast:15 -> rows 1,3
        DPP_ADD(s, 0x143, 0xc);   // row_bcast:31 -> rows 2,3
        float e = s - t;          // exclusive across lanes

        float* cb = (r & 1) ? buf1 : buf0;
        if (ldr)
            ((float4*)cb)[lane] = make_float4(e + q1, e + q2, e + q3, s);
        __builtin_amdgcn_wave_barrier();   // write visible before the gathers

        // Private per-lane box accumulation (no atomics).
        if (clsA >= 0 && y >= y1A && y < y2A) {
            float hi = cb[x2A];
            float lo = (x1A >= 0) ? cb[x1A] : 0.f;
            accA += hi - lo;
        }
        if (clsB >= 0 && y >= y1B && y < y2B) {
            float hi = cb[x2B];
            float lo = (x1B >= 0) ? cb[x1B] : 0.f;
            accB += hi - lo;
        }
        // No trailing barrier: row r+1 writes the other buffer; row r+2's
        // overwrite of cb is fenced by row r+1's wave_barrier.
        v = vn; vn = v2;
    }

    // One atomic per (wave, box): 1600 per block total.
    if (clsA >= 0) atomicAdd(&cls_sum[clsA], accA * wA);
    if (clsB >= 0) atomicAdd(&cls_sum[clsB], accB * wB);
    __syncthreads();

    // Epilogue: mean (already /cnt via bwgt) or negative-pixel fallback.
    if (tid < NC) {
        int cnt = cls_cnt[tid];
        float o = (cnt > 0) ? cls_sum[tid]
                            : plane[neg_y[b * NC + tid] * W + neg_x[b * NC + tid]];
        out[((size_t)b * NC + tid) * C + c] = o;
    }
}

extern "C" void kernel_launch(void* const* d_in, const int* in_sizes, int n_in,
                              void* d_out, int out_size, void* d_ws, size_t ws_size,
                              hipStream_t stream) {
    (void)in_sizes; (void)n_in; (void)d_ws; (void)ws_size; (void)out_size;
    vpe_kernel<<<dim3(B * C), dim3(T), 0, stream>>>(
        (const float*)d_in[0],   // features
        (const float*)d_in[1],   // boxes
        (const int*)d_in[2],     // gt_classes
        (const int*)d_in[3],     // neg_y
        (const int*)d_in[4],     // neg_x
        (const int*)d_in[5],     // image_h
        (const int*)d_in[6],     // image_w
        (float*)d_out);
}